// Round 5
// baseline (1256.475 us; speedup 1.0000x reference)
//
#include <hip/hip_runtime.h>

#define SEQ   784
#define PADT  16                            // front zero-pad rows (max dilation 16)
#define HSTR  40                            // shorts per row: 32 + 8 pad (80B, 16B-aligned rows)
#define NWAVE 8
#define BLK   (NWAVE * 64)
#define NROWB (PADT + 448)                  // 464 rows (part B); part A uses 416
#define LDS_BYTES (2 * NROWB * HSTR * 2)    // 74,240 B -> 2 blocks/CU (160 KB)

typedef __attribute__((ext_vector_type(8))) short  short8;
typedef __attribute__((ext_vector_type(4))) float  float4v;
typedef __attribute__((ext_vector_type(2))) unsigned int uint2v;

// pack two f32 -> bf16x2 (RNE), 5 VALU: 2x(bfe+add3) + v_perm
__device__ __forceinline__ unsigned int pk_rne(float lo, float hi) {
    unsigned int a = __float_as_uint(lo);
    unsigned int b = __float_as_uint(hi);
    a += 0x7fffu + ((a >> 16) & 1u);
    b += 0x7fffu + ((b >> 16) & 1u);
    return __builtin_amdgcn_perm(b, a, 0x07060302);  // [a.hi16 | b.hi16<<16]
}
__device__ __forceinline__ unsigned short f2bf(float f) {
    unsigned int a = __float_as_uint(f);
    a += 0x7fffu + ((a >> 16) & 1u);
    return (unsigned short)(a >> 16);
}
// tanh(a)*sigmoid(b); med3 clamp keeps exp2 finite
__device__ __forceinline__ float gate_fn(float a, float b) {
    a = __builtin_amdgcn_fmed3f(a, -12.f, 12.f);
    b = __builtin_amdgcn_fmed3f(b, -12.f, 12.f);
    float ta = __builtin_amdgcn_exp2f(-2.885390082f * a);   // e^{-2a}
    float tb = __builtin_amdgcn_exp2f(-1.442695041f * b);   // e^{-b}
    return (1.0f - ta) * __builtin_amdgcn_rcpf((1.0f + ta) * (1.0f + tb));
}

__global__ void __launch_bounds__(BLK) wavenet_kernel(
    const float* __restrict__ x,
    const float* __restrict__ w_causal,
    const float* __restrict__ b_causal,
    const float* __restrict__ w_dil,
    const float* __restrict__ b_dil,
    const float* __restrict__ w_res,
    const float* __restrict__ b_res,
    const float* __restrict__ w_out,
    const float* __restrict__ b_out,
    float* __restrict__ out)
{
    extern __shared__ unsigned short lds[];

    const int bid  = blockIdx.x;
    const int b    = bid >> 1;
    const int part = bid & 1;
    // part A: computes t in [0,400), outputs [0,400).   25 tiles, 416 rows.
    // part B: computes t in [336,784), outputs [400,784). 28 tiles, 464 rows.
    // halo 64 = full receptive field (2 + sum(dil) = 64) -> outputs exact.
    const int t0     = part ? 336 : 0;
    const int nrow   = part ? (PADT + 448) : (PADT + 400);
    const int ntt    = part ? 28 : 25;
    const int out_lo = part ? 400 : 0;
    const int n_out  = part ? 384 : 400;

    unsigned short* H0 = lds;                   // [nrow][HSTR] bf16
    unsigned short* H1 = lds + nrow * HSTR;
    float* XS = (float*)(H1 + PADT * HSTR);     // x staged fp32 in H1 data rows;
                                                // dead after causal conv (L0 writes H1
                                                // data cols 0..31; leftovers only in
                                                // pad cols, never read)
    const int tid = threadIdx.x;

    // ---- zero both H buffers ----
    {
        unsigned int* p = (unsigned int*)lds;
        const int n = nrow * HSTR;              // 2*nrow*HSTR shorts / 2
        for (int i = tid; i < n; i += BLK) p[i] = 0u;
    }
    __syncthreads();

    // ---- stage x: XS[r] = x[t0 + r - PADT] or 0 ----
    for (int r = tid; r < nrow; r += BLK) {
        int t = t0 + r - PADT;
        XS[r] = (t >= 0 && t < SEQ) ? x[b * SEQ + t] : 0.f;
    }
    __syncthreads();

    // ---- causal conv ----
    {
        int o = tid & 31;                       // invariant under += BLK
        float wc0 = w_causal[o * 2 + 0];
        float wc1 = w_causal[o * 2 + 1];
        float bc  = b_causal[o];
        const int span = nrow - PADT;
        for (int idx = tid; idx < span * 32; idx += BLK) {
            int r = PADT + (idx >> 5);
            float v = bc + wc0 * XS[r - 2] + wc1 * XS[r - 1];
            H0[r * HSTR + o] = f2bf(v);
        }
    }
    __syncthreads();

    const int lane = tid & 63;
    const int wave = tid >> 6;
    const int m    = lane & 15;   // A-row / B-col / D-col
    const int q    = lane >> 4;   // quad
    const int adr1 = (32 * (q & 1) + m) * 4;   // bpermute byte addrs (loop-invariant)
    const int adr2 = adr1 + 64;
    const int hi   = q >> 1;

    const int dil[10] = {1, 2, 4, 8, 16, 1, 2, 4, 8, 16};

    for (int L = 0; L < 10; ++L) {
        unsigned short* src = (L & 1) ? H1 : H0;
        unsigned short* dst = (L & 1) ? H0 : H1;
        const int d = dil[L];

        // ---- weight frags: vectorized fp32 loads -> packed bf16 ----
        short8 WA[4][2];
        #pragma unroll
        for (int rt = 0; rt < 4; ++rt) {
            const float4* wp = (const float4*)(w_dil + (((L * 64 + rt * 16 + m) * 32) + q * 8) * 2);
            float4 c0 = wp[0], c1 = wp[1], c2 = wp[2], c3 = wp[3];
            union { unsigned int i[4]; short8 v; } u0, u1;
            u0.i[0] = pk_rne(c0.x, c0.z); u0.i[1] = pk_rne(c1.x, c1.z);
            u0.i[2] = pk_rne(c2.x, c2.z); u0.i[3] = pk_rne(c3.x, c3.z);
            u1.i[0] = pk_rne(c0.y, c0.w); u1.i[1] = pk_rne(c1.y, c1.w);
            u1.i[2] = pk_rne(c2.y, c2.w); u1.i[3] = pk_rne(c3.y, c3.w);
            WA[rt][0] = u0.v; WA[rt][1] = u1.v;
        }
        short8 WR[2];
        #pragma unroll
        for (int rt = 0; rt < 2; ++rt) {
            const float4* wp = (const float4*)(w_res + (L * 32 + rt * 16 + m) * 32 + q * 8);
            float4 d0 = wp[0], d1 = wp[1];
            union { unsigned int i[4]; short8 v; } u;
            u.i[0] = pk_rne(d0.x, d0.y); u.i[1] = pk_rne(d0.z, d0.w);
            u.i[2] = pk_rne(d1.x, d1.y); u.i[3] = pk_rne(d1.z, d1.w);
            WR[rt] = u.v;
        }
        // biases -> accumulator-init vectors (C-layout row = q*4+r)
        float4v BDv[4], BRv[2];
        #pragma unroll
        for (int rt = 0; rt < 4; ++rt) {
            const float* bp = b_dil + L * 64 + rt * 16 + q * 4;
            BDv[rt] = (float4v){bp[0], bp[1], bp[2], bp[3]};
        }
        #pragma unroll
        for (int rt = 0; rt < 2; ++rt) {
            const float* bp = b_res + L * 32 + rt * 16 + q * 4;
            BRv[rt] = (float4v){bp[0], bp[1], bp[2], bp[3]};
        }

        // ---- incremental LDS pointers ----
        const int rowu0 = PADT + wave * 16 + m;
        const unsigned short* pBu = src + rowu0 * HSTR + q * 8;
        const unsigned short* pBs = pBu - d * HSTR;
        const unsigned short* pH  = src + rowu0 * HSTR + q * 4;
        unsigned short*       pD  = dst + rowu0 * HSTR + q * 4;
        const int step = NWAVE * 16 * HSTR;

        for (int tt = wave; tt < ntt; tt += NWAVE) {
            const short8 Bs = *(const short8*)pBs;
            const short8 Bu = *(const short8*)pBu;

            float4v a0 = BDv[0], a1 = BDv[1], a2 = BDv[2], a3 = BDv[3];
            a0 = __builtin_amdgcn_mfma_f32_16x16x32_bf16(WA[0][0], Bs, a0, 0, 0, 0);
            a0 = __builtin_amdgcn_mfma_f32_16x16x32_bf16(WA[0][1], Bu, a0, 0, 0, 0);
            a1 = __builtin_amdgcn_mfma_f32_16x16x32_bf16(WA[1][0], Bs, a1, 0, 0, 0);
            a1 = __builtin_amdgcn_mfma_f32_16x16x32_bf16(WA[1][1], Bu, a1, 0, 0, 0);
            a2 = __builtin_amdgcn_mfma_f32_16x16x32_bf16(WA[2][0], Bs, a2, 0, 0, 0);
            a2 = __builtin_amdgcn_mfma_f32_16x16x32_bf16(WA[2][1], Bu, a2, 0, 0, 0);
            a3 = __builtin_amdgcn_mfma_f32_16x16x32_bf16(WA[3][0], Bs, a3, 0, 0, 0);
            a3 = __builtin_amdgcn_mfma_f32_16x16x32_bf16(WA[3][1], Bu, a3, 0, 0, 0);

            // gate (biases already in acc): ch q*4+r (a0/a2), ch 16+q*4+r (a1/a3)
            float g00 = gate_fn(a0[0], a2[0]), g01 = gate_fn(a0[1], a2[1]);
            float g02 = gate_fn(a0[2], a2[2]), g03 = gate_fn(a0[3], a2[3]);
            float g10 = gate_fn(a1[0], a3[0]), g11 = gate_fn(a1[1], a3[1]);
            float g12 = gate_fn(a1[2], a3[2]), g13 = gate_fn(a1[3], a3[3]);
            int P0 = (int)pk_rne(g00, g01), P1 = (int)pk_rne(g02, g03);
            int P2 = (int)pk_rne(g10, g11), P3 = (int)pk_rne(g12, g13);

            // register transpose C-layout -> B-layout (verified in round 4)
            int A0 = __builtin_amdgcn_ds_bpermute(adr1, P0);
            int A1 = __builtin_amdgcn_ds_bpermute(adr1, P1);
            int A2 = __builtin_amdgcn_ds_bpermute(adr1, P2);
            int A3 = __builtin_amdgcn_ds_bpermute(adr1, P3);
            int C0 = __builtin_amdgcn_ds_bpermute(adr2, P0);
            int C1 = __builtin_amdgcn_ds_bpermute(adr2, P1);
            int C2 = __builtin_amdgcn_ds_bpermute(adr2, P2);
            int C3 = __builtin_amdgcn_ds_bpermute(adr2, P3);
            union { int i[4]; short8 v; } ug;
            ug.i[0] = hi ? A2 : A0; ug.i[1] = hi ? A3 : A1;
            ug.i[2] = hi ? C2 : C0; ug.i[3] = hi ? C3 : C1;
            const short8 Gf = ug.v;

            // residual: R = Wr*G + b_res (bias in acc init), then h' = h + R
            float4v r0 = BRv[0], r1 = BRv[1];
            r0 = __builtin_amdgcn_mfma_f32_16x16x32_bf16(WR[0], Gf, r0, 0, 0, 0);
            r1 = __builtin_amdgcn_mfma_f32_16x16x32_bf16(WR[1], Gf, r1, 0, 0, 0);

            const uint2v hu = *(const uint2v*)pH;
            const uint2v hv = *(const uint2v*)(pH + 16);
            float v00 = __uint_as_float(hu.x << 16)          + r0[0];
            float v01 = __uint_as_float(hu.x & 0xffff0000u)  + r0[1];
            float v02 = __uint_as_float(hu.y << 16)          + r0[2];
            float v03 = __uint_as_float(hu.y & 0xffff0000u)  + r0[3];
            float v10 = __uint_as_float(hv.x << 16)          + r1[0];
            float v11 = __uint_as_float(hv.x & 0xffff0000u)  + r1[1];
            float v12 = __uint_as_float(hv.y << 16)          + r1[2];
            float v13 = __uint_as_float(hv.y & 0xffff0000u)  + r1[3];
            uint2v n0 = {pk_rne(v00, v01), pk_rne(v02, v03)};
            uint2v n1 = {pk_rne(v10, v11), pk_rne(v12, v13)};
            *(uint2v*)pD        = n0;
            *(uint2v*)(pD + 16) = n1;

            pBu += step; pBs += step; pH += step; pD += step;
        }
        __syncthreads();
    }

    // ---- output proj (final h in H0; L=9 is odd -> dst was H0) ----
    {
        float wo[32];
        #pragma unroll
        for (int k = 0; k < 32; ++k) wo[k] = w_out[k];
        float bo = b_out[0];
        for (int i = tid; i < n_out; i += BLK) {
            int t = out_lo + i;
            const unsigned short* hp = H0 + (PADT + t - t0) * HSTR;
            float s = bo;
            #pragma unroll
            for (int kk = 0; kk < 32; kk += 4) {
                uint2v hh = *(const uint2v*)(hp + kk);
                s += wo[kk]     * __uint_as_float(hh.x << 16);
                s += wo[kk + 1] * __uint_as_float(hh.x & 0xffff0000u);
                s += wo[kk + 2] * __uint_as_float(hh.y << 16);
                s += wo[kk + 3] * __uint_as_float(hh.y & 0xffff0000u);
            }
            out[b * SEQ + t] = s;
        }
    }
}

extern "C" void kernel_launch(void* const* d_in, const int* in_sizes, int n_in,
                              void* d_out, int out_size, void* d_ws, size_t ws_size,
                              hipStream_t stream) {
    const float* x        = (const float*)d_in[0];
    const float* w_causal = (const float*)d_in[1];
    const float* b_causal = (const float*)d_in[2];
    const float* w_dil    = (const float*)d_in[3];
    const float* b_dil    = (const float*)d_in[4];
    const float* w_res    = (const float*)d_in[5];
    const float* b_res    = (const float*)d_in[6];
    const float* w_out    = (const float*)d_in[7];
    const float* b_out    = (const float*)d_in[8];
    float* out = (float*)d_out;

    const int B = in_sizes[0] / SEQ;  // 2048

    (void)hipFuncSetAttribute(reinterpret_cast<const void*>(wavenet_kernel),
                              hipFuncAttributeMaxDynamicSharedMemorySize, LDS_BYTES);

    wavenet_kernel<<<B * 2, BLK, LDS_BYTES, stream>>>(
        x, w_causal, b_causal, w_dil, b_dil, w_res, b_res, w_out, b_out, out);
}

// Round 6
// 752.603 us; speedup vs baseline: 1.6695x; 1.6695x over previous
//
#include <hip/hip_runtime.h>

#define SEQ   784
#define PADT  16                    // front zero-pad rows (max dilation 16)
#define NROW  (PADT + SEQ)          // 800
#define HSTR  40                    // shorts per row: 32 + 8 pad (80B rows, 16B-aligned)
#define NWAVE 8
#define BLK   (NWAVE * 64)
#define NTT   49                    // 49 time tiles of 16
#define NSLOT 7                     // ceil(49/8); slot 6 active on wave 0 only
#define LDS_BYTES (NROW * HSTR * 2) // 64,000 B -> 2 blocks/CU

typedef __attribute__((ext_vector_type(8))) short  short8;
typedef __attribute__((ext_vector_type(4))) float  float4v;
typedef __attribute__((ext_vector_type(2))) unsigned int uint2v;

// pack two f32 -> bf16x2 (RNE)
__device__ __forceinline__ unsigned int pk_rne(float lo, float hi) {
    unsigned int a = __float_as_uint(lo);
    unsigned int b = __float_as_uint(hi);
    a += 0x7fffu + ((a >> 16) & 1u);
    b += 0x7fffu + ((b >> 16) & 1u);
    return __builtin_amdgcn_perm(b, a, 0x07060302);  // [a.hi16 | b.hi16<<16]
}
__device__ __forceinline__ unsigned short f2bf(float f) {
    unsigned int a = __float_as_uint(f);
    a += 0x7fffu + ((a >> 16) & 1u);
    return (unsigned short)(a >> 16);
}
// tanh(a)*sigmoid(b); med3 clamp keeps exp2 finite
__device__ __forceinline__ float gate_fn(float a, float b) {
    a = __builtin_amdgcn_fmed3f(a, -12.f, 12.f);
    b = __builtin_amdgcn_fmed3f(b, -12.f, 12.f);
    float ta = __builtin_amdgcn_exp2f(-2.885390082f * a);   // e^{-2a}
    float tb = __builtin_amdgcn_exp2f(-1.442695041f * b);   // e^{-b}
    return (1.0f - ta) * __builtin_amdgcn_rcpf((1.0f + ta) * (1.0f + tb));
}

__global__ void __launch_bounds__(BLK, 4) wavenet_kernel(
    const float* __restrict__ x,
    const float* __restrict__ w_causal,
    const float* __restrict__ b_causal,
    const float* __restrict__ w_dil,
    const float* __restrict__ b_dil,
    const float* __restrict__ w_res,
    const float* __restrict__ b_res,
    const float* __restrict__ w_out,
    const float* __restrict__ b_out,
    float* __restrict__ out)
{
    extern __shared__ unsigned short lds[];
    unsigned short* H = lds;                    // single [NROW][HSTR] bf16 buffer

    const int tid = threadIdx.x;
    const int b   = blockIdx.x;

    // ---- zero pad rows (only rows 0..15 are ever read before being written;
    //      pad cols 32..39 are never read by any access pattern) ----
    {
        unsigned int* p = (unsigned int*)H;
        for (int i = tid; i < PADT * HSTR / 2; i += BLK) p[i] = 0u;
    }

    // ---- causal conv straight from global x (L1-cached, 3.1 KB/block) ----
    {
        int o = tid & 31;                       // invariant under += BLK
        float wc0 = w_causal[o * 2 + 0];
        float wc1 = w_causal[o * 2 + 1];
        float bc  = b_causal[o];
        const float* xb = x + b * SEQ;
        for (int idx = tid; idx < SEQ * 32; idx += BLK) {
            int t = idx >> 5;
            float v = bc;
            if (t >= 2) v += wc0 * xb[t - 2];
            if (t >= 1) v += wc1 * xb[t - 1];
            H[(PADT + t) * HSTR + o] = f2bf(v);
        }
    }
    __syncthreads();

    const int lane = tid & 63;
    const int wave = tid >> 6;
    const int m    = lane & 15;   // A-row / B-col / D-col
    const int q    = lane >> 4;   // quad
    const int adr1 = (32 * (q & 1) + m) * 4;   // bpermute byte addrs (invariant)
    const int adr2 = adr1 + 64;
    const int hi   = q >> 1;

    const int dil[10] = {1, 2, 4, 8, 16, 1, 2, 4, 8, 16};

    for (int L = 0; L < 10; ++L) {
        const int d = dil[L];

        // ---- weight frags: vectorized fp32 loads -> packed bf16 (verified R5) ----
        short8 WA[4][2];
        #pragma unroll
        for (int rt = 0; rt < 4; ++rt) {
            const float4* wp = (const float4*)(w_dil + (((L * 64 + rt * 16 + m) * 32) + q * 8) * 2);
            float4 c0 = wp[0], c1 = wp[1], c2 = wp[2], c3 = wp[3];
            union { unsigned int i[4]; short8 v; } u0, u1;
            u0.i[0] = pk_rne(c0.x, c0.z); u0.i[1] = pk_rne(c1.x, c1.z);
            u0.i[2] = pk_rne(c2.x, c2.z); u0.i[3] = pk_rne(c3.x, c3.z);
            u1.i[0] = pk_rne(c0.y, c0.w); u1.i[1] = pk_rne(c1.y, c1.w);
            u1.i[2] = pk_rne(c2.y, c2.w); u1.i[3] = pk_rne(c3.y, c3.w);
            WA[rt][0] = u0.v; WA[rt][1] = u1.v;
        }
        short8 WR[2];
        #pragma unroll
        for (int rt = 0; rt < 2; ++rt) {
            const float4* wp = (const float4*)(w_res + (L * 32 + rt * 16 + m) * 32 + q * 8);
            float4 d0 = wp[0], d1 = wp[1];
            union { unsigned int i[4]; short8 v; } u;
            u.i[0] = pk_rne(d0.x, d0.y); u.i[1] = pk_rne(d0.z, d0.w);
            u.i[2] = pk_rne(d1.x, d1.y); u.i[3] = pk_rne(d1.z, d1.w);
            WR[rt] = u.v;
        }
        // biases -> accumulator-init vectors (C-layout row = q*4+r)
        float4v BDv[4], BRv[2];
        #pragma unroll
        for (int rt = 0; rt < 4; ++rt) {
            const float* bp = b_dil + L * 64 + rt * 16 + q * 4;
            BDv[rt] = (float4v){bp[0], bp[1], bp[2], bp[3]};
        }
        #pragma unroll
        for (int rt = 0; rt < 2; ++rt) {
            const float* bp = b_res + L * 32 + rt * 16 + q * 4;
            BRv[rt] = (float4v){bp[0], bp[1], bp[2], bp[3]};
        }

        // ---- compute phase: all reads of old h; results held in registers ----
        uint2v N0[NSLOT], N1[NSLOT];
        const int rowu0 = PADT + wave * 16 + m;
        const int sstep = NWAVE * 16 * HSTR;    // row stride between a wave's slots

        #pragma unroll
        for (int s = 0; s < NSLOT; ++s) {
            if (s < NSLOT - 1 || wave == 0) {   // slot 6: wave 0 only (wave-uniform)
                const unsigned short* pBu = H + (rowu0 + s * NWAVE * 16) * HSTR + q * 8;
                const short8 Bs = *(const short8*)(pBu - d * HSTR);
                const short8 Bu = *(const short8*)pBu;
                const unsigned short* pH4 = H + (rowu0 + s * NWAVE * 16) * HSTR + q * 4;
                const uint2v hu = *(const uint2v*)pH4;
                const uint2v hv = *(const uint2v*)(pH4 + 16);

                float4v a0 = BDv[0], a1 = BDv[1], a2 = BDv[2], a3 = BDv[3];
                a0 = __builtin_amdgcn_mfma_f32_16x16x32_bf16(WA[0][0], Bs, a0, 0, 0, 0);
                a0 = __builtin_amdgcn_mfma_f32_16x16x32_bf16(WA[0][1], Bu, a0, 0, 0, 0);
                a1 = __builtin_amdgcn_mfma_f32_16x16x32_bf16(WA[1][0], Bs, a1, 0, 0, 0);
                a1 = __builtin_amdgcn_mfma_f32_16x16x32_bf16(WA[1][1], Bu, a1, 0, 0, 0);
                a2 = __builtin_amdgcn_mfma_f32_16x16x32_bf16(WA[2][0], Bs, a2, 0, 0, 0);
                a2 = __builtin_amdgcn_mfma_f32_16x16x32_bf16(WA[2][1], Bu, a2, 0, 0, 0);
                a3 = __builtin_amdgcn_mfma_f32_16x16x32_bf16(WA[3][0], Bs, a3, 0, 0, 0);
                a3 = __builtin_amdgcn_mfma_f32_16x16x32_bf16(WA[3][1], Bu, a3, 0, 0, 0);

                // gate (biases already in acc): ch q*4+r (a0/a2), ch 16+q*4+r (a1/a3)
                float g00 = gate_fn(a0[0], a2[0]), g01 = gate_fn(a0[1], a2[1]);
                float g02 = gate_fn(a0[2], a2[2]), g03 = gate_fn(a0[3], a2[3]);
                float g10 = gate_fn(a1[0], a3[0]), g11 = gate_fn(a1[1], a3[1]);
                float g12 = gate_fn(a1[2], a3[2]), g13 = gate_fn(a1[3], a3[3]);
                int P0 = (int)pk_rne(g00, g01), P1 = (int)pk_rne(g02, g03);
                int P2 = (int)pk_rne(g10, g11), P3 = (int)pk_rne(g12, g13);

                // register transpose C-layout -> B-layout (verified R4/R5)
                int A0 = __builtin_amdgcn_ds_bpermute(adr1, P0);
                int A1 = __builtin_amdgcn_ds_bpermute(adr1, P1);
                int A2 = __builtin_amdgcn_ds_bpermute(adr1, P2);
                int A3 = __builtin_amdgcn_ds_bpermute(adr1, P3);
                int C0 = __builtin_amdgcn_ds_bpermute(adr2, P0);
                int C1 = __builtin_amdgcn_ds_bpermute(adr2, P1);
                int C2 = __builtin_amdgcn_ds_bpermute(adr2, P2);
                int C3 = __builtin_amdgcn_ds_bpermute(adr2, P3);
                union { int i[4]; short8 v; } ug;
                ug.i[0] = hi ? A2 : A0; ug.i[1] = hi ? A3 : A1;
                ug.i[2] = hi ? C2 : C0; ug.i[3] = hi ? C3 : C1;
                const short8 Gf = ug.v;

                // residual: R = Wr*G + b_res (bias in acc init), then h' = h + R
                float4v r0 = BRv[0], r1 = BRv[1];
                r0 = __builtin_amdgcn_mfma_f32_16x16x32_bf16(WR[0], Gf, r0, 0, 0, 0);
                r1 = __builtin_amdgcn_mfma_f32_16x16x32_bf16(WR[1], Gf, r1, 0, 0, 0);

                float v00 = __uint_as_float(hu.x << 16)          + r0[0];
                float v01 = __uint_as_float(hu.x & 0xffff0000u)  + r0[1];
                float v02 = __uint_as_float(hu.y << 16)          + r0[2];
                float v03 = __uint_as_float(hu.y & 0xffff0000u)  + r0[3];
                float v10 = __uint_as_float(hv.x << 16)          + r1[0];
                float v11 = __uint_as_float(hv.x & 0xffff0000u)  + r1[1];
                float v12 = __uint_as_float(hv.y << 16)          + r1[2];
                float v13 = __uint_as_float(hv.y & 0xffff0000u)  + r1[3];
                N0[s] = (uint2v){pk_rne(v00, v01), pk_rne(v02, v03)};
                N1[s] = (uint2v){pk_rne(v10, v11), pk_rne(v12, v13)};
            }
        }
        __syncthreads();   // all old-h reads complete

        // ---- write phase: in-place update ----
        #pragma unroll
        for (int s = 0; s < NSLOT; ++s) {
            if (s < NSLOT - 1 || wave == 0) {
                unsigned short* pD = H + (rowu0 + s * NWAVE * 16) * HSTR + q * 4;
                *(uint2v*)pD        = N0[s];
                *(uint2v*)(pD + 16) = N1[s];
            }
        }
        __syncthreads();
    }

    // ---- output proj: logits[t] = sum_k wo[k]*h[k][t] + bo ----
    {
        float wo[32];
        #pragma unroll
        for (int k = 0; k < 32; ++k) wo[k] = w_out[k];
        float bo = b_out[0];
        for (int t = tid; t < SEQ; t += BLK) {
            const unsigned short* hp = H + (PADT + t) * HSTR;
            float s = bo;
            #pragma unroll
            for (int kk = 0; kk < 32; kk += 4) {
                uint2v hh = *(const uint2v*)(hp + kk);
                s += wo[kk]     * __uint_as_float(hh.x << 16);
                s += wo[kk + 1] * __uint_as_float(hh.x & 0xffff0000u);
                s += wo[kk + 2] * __uint_as_float(hh.y << 16);
                s += wo[kk + 3] * __uint_as_float(hh.y & 0xffff0000u);
            }
            out[b * SEQ + t] = s;
        }
    }
}

extern "C" void kernel_launch(void* const* d_in, const int* in_sizes, int n_in,
                              void* d_out, int out_size, void* d_ws, size_t ws_size,
                              hipStream_t stream) {
    const float* x        = (const float*)d_in[0];
    const float* w_causal = (const float*)d_in[1];
    const float* b_causal = (const float*)d_in[2];
    const float* w_dil    = (const float*)d_in[3];
    const float* b_dil    = (const float*)d_in[4];
    const float* w_res    = (const float*)d_in[5];
    const float* b_res    = (const float*)d_in[6];
    const float* w_out    = (const float*)d_in[7];
    const float* b_out    = (const float*)d_in[8];
    float* out = (float*)d_out;

    const int B = in_sizes[0] / SEQ;  // 2048

    wavenet_kernel<<<B, BLK, LDS_BYTES, stream>>>(
        x, w_causal, b_causal, w_dil, b_dil, w_res, b_res, w_out, b_out, out);
}